// Round 1
// baseline (325.208 us; speedup 1.0000x reference)
//
#include <hip/hip_runtime.h>
#include <stdint.h>

#define N_NODES 4096
#define K_NN    40
#define B_CLOUDS 8
#define F_IN    8
#define H_DIM   64
#define O_DIM   128

#define OUT_FEAT_ELEMS (B_CLOUDS * N_NODES * O_DIM)   // 4194304
#define EDGES          (B_CLOUDS * N_NODES * K_NN)    // 1310720

typedef short bf16x8 __attribute__((ext_vector_type(8)));
typedef float f32x4  __attribute__((ext_vector_type(4)));

__device__ __forceinline__ unsigned short f2bf(float f) {
    unsigned u = __float_as_uint(f);
    unsigned r = (u + 0x7FFFu + ((u >> 16) & 1u)) >> 16;   // RNE
    return (unsigned short)r;
}

// wave_shr:1 — lane i receives lane i-1's value, VALU DPP (no DS round-trip).
// Lane 0 gets 0 (bound_ctrl); harmless: lane 0 sentinel always keeps.
__device__ __forceinline__ unsigned shr1_dpp(unsigned v) {
    return (unsigned)__builtin_amdgcn_update_dpp(0, (int)v, 0x138, 0xF, 0xF, true);
}

// One sorted-insert step for one target's list. mask bits consumed ascending,
// so per-list insert order is IDENTICAL to the single-target version
// (bit-exact same final list).
#define INS_STEP(mask_, dreg_, Rhi_, Rlo_)                                         \
    {                                                                              \
        const int src = (int)__builtin_ctzll(mask_);                               \
        mask_ &= mask_ - 1;                                                        \
        const unsigned long long kb =                                              \
            ((unsigned long long)(unsigned)__builtin_amdgcn_readlane((int)(dreg_), src) << 32) \
            | (unsigned)((c << 6) | src);                                          \
        const unsigned long long RP = ((unsigned long long)Rhi_ << 32) | Rlo_;     \
        const bool keep = (RP <= kb);                                              \
        const unsigned uplo = shr1_dpp(Rlo_);                                      \
        const unsigned uphi = shr1_dpp(Rhi_);                                      \
        const unsigned long long up = ((unsigned long long)uphi << 32) | uplo;     \
        const unsigned long long mx = (up > kb) ? up : kb;                         \
        const unsigned long long nw = keep ? RP : mx;                              \
        Rhi_ = (unsigned)(nw >> 32);                                               \
        Rlo_ = (unsigned)nw;                                                       \
    }

// ---------------------------------------------------------------------------
// Kernel A: exact KNN v4 — TWO targets per wave. The single-target version was
// latency-bound on the serial insert chain (derived VALUBusy ~100% == ~50%
// true issue on SIMD-32; occupancy thread-capped at 8 waves/SIMD, so TLP
// can't fill the stalls). Two independent lists per wave give the scheduler
// two independent dependency chains to interleave in the common-case loop.
// iA even, iB = iA+1: same self-chunk, shared LDS position reads.
// ---------------------------------------------------------------------------
__global__ __launch_bounds__(1024) void knn_kernel(const float* __restrict__ pos,
                                                   float* __restrict__ out)
{
    __shared__ float px[N_NODES];
    __shared__ float py[N_NODES];
    __shared__ float pz[N_NODES];

    const int b  = blockIdx.x >> 7;           // 128 blocks per cloud
    const int i0 = (blockIdx.x & 127) << 5;   // 32 targets per block
    const float* posb = pos + (size_t)b * N_NODES * 3;

    for (int t = threadIdx.x; t < N_NODES * 3; t += 1024) {
        float v = posb[t];
        int node = t / 3;
        int c = t - node * 3;
        if (c == 0) px[node] = v;
        else if (c == 1) py[node] = v;
        else pz[node] = v;
    }
    __syncthreads();

    const int wave = threadIdx.x >> 6;
    const int lane = threadIdx.x & 63;
    const int iA = i0 + (wave << 1);          // even
    const int iB = iA + 1;                    // same 64-chunk as iA
    const int ci = iA >> 6;                   // chunk containing both selves
    const int liA = iA & 63;
    const int liB = iB & 63;

    const float pax = px[iA], pay = py[iA], paz = pz[iA];
    const float pbx = px[iB], pby = py[iB], pbz = pz[iB];

    // sorted-ascending u64 keys; lane 0 = 0-sentinel
    unsigned RAhi = (lane == 0) ? 0u : 0xFFFFFFFFu;
    unsigned RAlo = (lane == 0) ? 0u : 0xFFFFFFFFu;
    unsigned RBhi = RAhi, RBlo = RAlo;

    for (int c = 0; c < 64; ++c) {
        const int j = (c << 6) | lane;
        const float qx = px[j], qy = py[j], qz = pz[j];
        // bitwise-exact fp32: ((dx*dx + dy*dy) + dz*dz), no FMA contraction
        float dxA = __fsub_rn(pax, qx);
        float dyA = __fsub_rn(pay, qy);
        float dzA = __fsub_rn(paz, qz);
        float d2A = __fadd_rn(__fadd_rn(__fmul_rn(dxA, dxA), __fmul_rn(dyA, dyA)),
                              __fmul_rn(dzA, dzA));
        float dxB = __fsub_rn(pbx, qx);
        float dyB = __fsub_rn(pby, qy);
        float dzB = __fsub_rn(pbz, qz);
        float d2B = __fadd_rn(__fadd_rn(__fmul_rn(dxB, dxB), __fmul_rn(dyB, dyB)),
                              __fmul_rn(dzB, dzB));
        unsigned dA = __float_as_uint(d2A);
        unsigned dB = __float_as_uint(d2B);
        if (c == ci) {                        // wave-uniform: 1 of 64 chunks
            if (lane == liA) dA = 0xFFFFFFFFu;   // self sorts after all real
            if (lane == liB) dB = 0xFFFFFFFFu;
        }

        // thresholds = 40th-smallest real key (lane 40; lane 0 is sentinel)
        const unsigned a40hi = (unsigned)__builtin_amdgcn_readlane((int)RAhi, 40);
        const unsigned a40lo = (unsigned)__builtin_amdgcn_readlane((int)RAlo, 40);
        const unsigned b40hi = (unsigned)__builtin_amdgcn_readlane((int)RBhi, 40);
        const unsigned b40lo = (unsigned)__builtin_amdgcn_readlane((int)RBlo, 40);
        const unsigned long long r40A = ((unsigned long long)a40hi << 32) | a40lo;
        const unsigned long long r40B = ((unsigned long long)b40hi << 32) | b40lo;
        const unsigned long long keyA = ((unsigned long long)dA << 32) | (unsigned)j;
        const unsigned long long keyB = ((unsigned long long)dB << 32) | (unsigned)j;

        unsigned long long maskA = __ballot(keyA < r40A);
        unsigned long long maskB = __ballot(keyB < r40B);

        // common case: both lists inserting -> two independent chains in one
        // basic block, scheduler interleaves them (2x ILP on the stall chain)
        while (maskA && maskB) {
            INS_STEP(maskA, dA, RAhi, RAlo);
            INS_STEP(maskB, dB, RBhi, RBlo);
        }
        while (maskA) INS_STEP(maskA, dA, RAhi, RAlo);
        while (maskB) INS_STEP(maskB, dB, RBhi, RBlo);
    }

    // Emit edges from lanes 1..40: src = global neighbor id, tgt = target id
    float* src_out = out + OUT_FEAT_ELEMS;
    float* tgt_out = src_out + EDGES;
    const int giA = b * N_NODES + iA;
    const int giB = giA + 1;
    const unsigned el = (unsigned)(lane - 1);
    if (el < K_NN) {
        src_out[(size_t)giA * K_NN + el] = (float)(b * N_NODES + (int)RAlo);
        tgt_out[(size_t)giA * K_NN + el] = (float)giA;
        src_out[(size_t)giB * K_NN + el] = (float)(b * N_NODES + (int)RBlo);
        tgt_out[(size_t)giB * K_NN + el] = (float)giB;
    }
}

// ---------------------------------------------------------------------------
// Kernel P: precompute W2 and W1 bf16 B-fragments into d_ws — R14, proven.
// ---------------------------------------------------------------------------
__global__ __launch_bounds__(256) void prep_kernel(const float* __restrict__ W2,
                                                   const float* __restrict__ W1,
                                                   unsigned short* __restrict__ ws)
{
    const int idx = blockIdx.x * 256 + threadIdx.x;   // 0..10239
    if (idx < 8192) {
        const int j    = idx & 7;
        const int lane = (idx >> 3) & 63;
        const int kt   = (idx >> 9) & 1;
        const int nt   = idx >> 10;
        const int k = kt * 32 + (lane >> 4) * 8 + j;
        const int n = nt * 16 + (lane & 15);
        ws[idx] = f2bf(W2[k * O_DIM + n]);
    } else if (idx < 8192 + 2048) {
        const int t = idx - 8192;
        const int j    = t & 7;
        const int lane = (t >> 3) & 63;
        const int nt   = t >> 9;          // 0..3
        const int k = (lane >> 4) * 8 + j;          // 0..31
        const int n = nt * 16 + (lane & 15);        // hidden channel
        ws[idx] = (k < 11) ? f2bf(W1[k * H_DIM + n]) : (unsigned short)0;
    }
}

// ---------------------------------------------------------------------------
// Kernel B: per-edge MLP, both layers MFMA — UNCHANGED from R14 (proven).
// ---------------------------------------------------------------------------
#define HSTR 72   // Hh row stride (bf16): 144 B
#define KSTR 40   // msg row stride (bf16): 80 B, 16B-aligned rows

__global__ __launch_bounds__(256, 4) void conv_kernel(
    const float* __restrict__ x, const float* __restrict__ pos,
    const unsigned short* __restrict__ w2f,   // d_ws: w2 frags [0,8192)
    const unsigned short* __restrict__ w1f,   // d_ws: w1 frags [8192,10240)
    const float* __restrict__ b1, const float* __restrict__ b2,
    float* __restrict__ out)
{
    __shared__ __align__(16) unsigned short Hh[4][48 * HSTR];    // 27648 B

    const int b    = blockIdx.x >> 10;
    const int i0   = (blockIdx.x & 1023) << 2;
    const int wave = threadIdx.x >> 6;
    const int lane = threadIdx.x & 63;
    const int quad = lane >> 4;
    const int col  = lane & 15;
    const int i    = i0 + wave;
    const int gi   = b * N_NODES + i;

    unsigned short* Hw = Hh[wave];

    // ---- phase 1: lane n (<48) gathers message row n, stages bf16 to LDS ----
    const float* src_edges = out + OUT_FEAT_ELEMS;
    if (lane < 48) {
        int j;
        if (lane < K_NN) j = (int)src_edges[(size_t)gi * K_NN + lane] - b * N_NODES;
        else             j = i;   // rows 40..47: self row + pad dups (max-safe)
        const float* xr = x + ((size_t)b * N_NODES + j) * F_IN;
        float4 xa = *(const float4*)xr;
        float4 xb = *(const float4*)(xr + 4);
        const float* pj = pos + ((size_t)b * N_NODES + j) * 3;
        const float* pi = pos + ((size_t)b * N_NODES + i) * 3;
        unsigned w[16];
#pragma unroll
        for (int t = 0; t < 16; ++t) w[t] = 0;
        w[0] = (unsigned)f2bf(xa.x) | ((unsigned)f2bf(xa.y) << 16);
        w[1] = (unsigned)f2bf(xa.z) | ((unsigned)f2bf(xa.w) << 16);
        w[2] = (unsigned)f2bf(xb.x) | ((unsigned)f2bf(xb.y) << 16);
        w[3] = (unsigned)f2bf(xb.z) | ((unsigned)f2bf(xb.w) << 16);
        w[4] = (unsigned)f2bf(pj[0] - pi[0]) | ((unsigned)f2bf(pj[1] - pi[1]) << 16);
        w[5] = (unsigned)f2bf(pj[2] - pi[2]);
        unsigned* mrow = (unsigned*)(Hw + lane * KSTR);
        *(uint4*)(mrow)      = make_uint4(w[0], w[1], w[2], w[3]);
        *(uint4*)(mrow + 4)  = make_uint4(w[4], w[5], w[6], w[7]);
        *(uint4*)(mrow + 8)  = make_uint4(w[8], w[9], w[10], w[11]);
        *(uint4*)(mrow + 12) = make_uint4(w[12], w[13], w[14], w[15]);
    }
    // same-wave ds_write -> ds_read: ordered by lgkmcnt, no barrier needed

    // ---- layer 1 via MFMA: H[48x64] = msg[48x32] . W1[32x64] ----
    bf16x8 Am[3];
#pragma unroll
    for (int mt = 0; mt < 3; ++mt)
        Am[mt] = *(const bf16x8*)&Hw[(mt * 16 + col) * KSTR + quad * 8];

    const bf16x8* W1f = (const bf16x8*)w1f;
    float hreg[12][4];
#pragma unroll
    for (int nt = 0; nt < 4; ++nt) {
        bf16x8 Bn = W1f[nt * 64 + lane];
        const float bias = b1[nt * 16 + col];
        f32x4 d0 = {bias, bias, bias, bias};
        f32x4 d1 = d0, d2 = d0;
        d0 = __builtin_amdgcn_mfma_f32_16x16x32_bf16(Am[0], Bn, d0, 0, 0, 0);
        d1 = __builtin_amdgcn_mfma_f32_16x16x32_bf16(Am[1], Bn, d1, 0, 0, 0);
        d2 = __builtin_amdgcn_mfma_f32_16x16x32_bf16(Am[2], Bn, d2, 0, 0, 0);
#pragma unroll
        for (int r = 0; r < 4; ++r) {
            hreg[nt * 3 + 0][r] = fmaxf(d0[r], 0.0f);
            hreg[nt * 3 + 1][r] = fmaxf(d1[r], 0.0f);
            hreg[nt * 3 + 2][r] = fmaxf(d2[r], 0.0f);
        }
    }

    // msg fully consumed -> overwrite region as Hh[row][hidden]
#pragma unroll
    for (int nt = 0; nt < 4; ++nt)
#pragma unroll
        for (int mt = 0; mt < 3; ++mt)
#pragma unroll
            for (int r = 0; r < 4; ++r)
                Hw[(mt * 16 + quad * 4 + r) * HSTR + nt * 16 + col] =
                    f2bf(hreg[nt * 3 + mt][r]);

    // ---- layer 2 via MFMA ----
    bf16x8 Af[3][2];
#pragma unroll
    for (int mt = 0; mt < 3; ++mt)
#pragma unroll
        for (int kt = 0; kt < 2; ++kt)
            Af[mt][kt] = *(const bf16x8*)&Hw[(mt * 16 + col) * HSTR + kt * 32 + quad * 8];

    const bf16x8* Bws = (const bf16x8*)w2f;
#pragma unroll
    for (int nt = 0; nt < 8; ++nt) {
        bf16x8 B0 = Bws[nt * 128 + lane];
        bf16x8 B1 = Bws[nt * 128 + 64 + lane];

        f32x4 c0 = {0.f, 0.f, 0.f, 0.f};
        f32x4 c1 = {0.f, 0.f, 0.f, 0.f};
        f32x4 c2 = {0.f, 0.f, 0.f, 0.f};
        c0 = __builtin_amdgcn_mfma_f32_16x16x32_bf16(Af[0][0], B0, c0, 0, 0, 0);
        c1 = __builtin_amdgcn_mfma_f32_16x16x32_bf16(Af[1][0], B0, c1, 0, 0, 0);
        c2 = __builtin_amdgcn_mfma_f32_16x16x32_bf16(Af[2][0], B0, c2, 0, 0, 0);
        c0 = __builtin_amdgcn_mfma_f32_16x16x32_bf16(Af[0][1], B1, c0, 0, 0, 0);
        c1 = __builtin_amdgcn_mfma_f32_16x16x32_bf16(Af[1][1], B1, c1, 0, 0, 0);
        c2 = __builtin_amdgcn_mfma_f32_16x16x32_bf16(Af[2][1], B1, c2, 0, 0, 0);

        float vm = c0[0];
        vm = fmaxf(vm, c0[1]); vm = fmaxf(vm, c0[2]); vm = fmaxf(vm, c0[3]);
        vm = fmaxf(vm, c1[0]); vm = fmaxf(vm, c1[1]); vm = fmaxf(vm, c1[2]); vm = fmaxf(vm, c1[3]);
        vm = fmaxf(vm, c2[0]); vm = fmaxf(vm, c2[1]); vm = fmaxf(vm, c2[2]); vm = fmaxf(vm, c2[3]);
        vm = fmaxf(vm, __shfl_xor(vm, 16));
        vm = fmaxf(vm, __shfl_xor(vm, 32));
        vm += b2[nt * 16 + col];

        if (lane < 16) out[(size_t)gi * O_DIM + nt * 16 + lane] = vm;
    }
}

// ---------------------------------------------------------------------------
extern "C" void kernel_launch(void* const* d_in, const int* in_sizes, int n_in,
                              void* d_out, int out_size, void* d_ws, size_t ws_size,
                              hipStream_t stream) {
    const float* x   = (const float*)d_in[0];
    const float* pos = (const float*)d_in[1];
    const float* W1  = (const float*)d_in[2];
    const float* b1  = (const float*)d_in[3];
    const float* W2  = (const float*)d_in[4];
    const float* b2  = (const float*)d_in[5];
    float* out = (float*)d_out;
    unsigned short* ws = (unsigned short*)d_ws;   // 10240 bf16 = 20.5 KB

    prep_kernel<<<40, 256, 0, stream>>>(W2, W1, ws);
    knn_kernel<<<(B_CLOUDS * N_NODES) / 32, 1024, 0, stream>>>(pos, out);
    conv_kernel<<<(B_CLOUDS * N_NODES) / 4, 256, 0, stream>>>(
        x, pos, ws, ws + 8192, b1, b2, out);
}

// Round 2
// 223.854 us; speedup vs baseline: 1.4528x; 1.4528x over previous
//
#include <hip/hip_runtime.h>
#include <stdint.h>

#define N_NODES 4096
#define K_NN    40
#define B_CLOUDS 8
#define F_IN    8
#define H_DIM   64
#define O_DIM   128

#define OUT_FEAT_ELEMS (B_CLOUDS * N_NODES * O_DIM)   // 4194304
#define EDGES          (B_CLOUDS * N_NODES * K_NN)    // 1310720

typedef short bf16x8 __attribute__((ext_vector_type(8)));
typedef float f32x4  __attribute__((ext_vector_type(4)));

__device__ __forceinline__ unsigned short f2bf(float f) {
    unsigned u = __float_as_uint(f);
    unsigned r = (u + 0x7FFFu + ((u >> 16) & 1u)) >> 16;   // RNE
    return (unsigned short)r;
}

// wave_shr:1 — lane i receives lane i-1's value, VALU DPP (no DS round-trip).
// Lane 0 gets 0 (bound_ctrl); harmless: lane 0 sentinel always keeps.
__device__ __forceinline__ unsigned shr1_dpp(unsigned v) {
    return (unsigned)__builtin_amdgcn_update_dpp(0, (int)v, 0x138, 0xF, 0xF, true);
}

// One sorted-insert step (proven v3 machinery). mask bits consumed ascending,
// keys (d2<<32|j) ascending across lanes, lane 0 = 0-sentinel.
#define INS_STEP(mask_, dreg_, Rhi_, Rlo_)                                         \
    {                                                                              \
        const int src = (int)__builtin_ctzll(mask_);                               \
        mask_ &= mask_ - 1;                                                        \
        const unsigned long long kb =                                              \
            ((unsigned long long)(unsigned)__builtin_amdgcn_readlane((int)(dreg_), src) << 32) \
            | (unsigned)((c << 6) | src);                                          \
        const unsigned long long RP = ((unsigned long long)Rhi_ << 32) | Rlo_;     \
        const bool keep = (RP <= kb);                                              \
        const unsigned uplo = shr1_dpp(Rlo_);                                      \
        const unsigned uphi = shr1_dpp(Rhi_);                                      \
        const unsigned long long up = ((unsigned long long)uphi << 32) | uplo;     \
        const unsigned long long mx = (up > kb) ? up : kb;                         \
        const unsigned long long nw = keep ? RP : mx;                              \
        Rhi_ = (unsigned)(nw >> 32);                                               \
        Rlo_ = (unsigned)nw;                                                       \
    }

// ---------------------------------------------------------------------------
// Kernel A: exact KNN v5 — three phases, ~2x fewer instructions than v3.
//   P1: per-lane top-4 of its 64 candidates (branch-free min/max chain).
//   RS: radix-select t = 40th-smallest of kept 256. Since kept ⊆ all,
//       t >= true 40th ALWAYS → {d2<=t} ⊇ true top-40 unconditionally.
//   P2: v3 sorted-insert with FIXED threshold t: only ~40-44 true qualifiers
//       enter the insert loop (vs ~250 with the running stale threshold).
//       List keeps the 63 smallest inserted → ranks 1..40 exact even with
//       extra qualifiers. Exact (d2,j) lexicographic order == top_k ties.
// ---------------------------------------------------------------------------
__global__ __launch_bounds__(1024) void knn_kernel(const float* __restrict__ pos,
                                                   float* __restrict__ out)
{
    __shared__ float4 ppos[N_NODES];   // 64 KB; 2 blocks/CU = 128 KB <= 160 KB

    const int b  = blockIdx.x >> 8;           // 256 blocks per cloud
    const int i0 = (blockIdx.x & 255) << 4;   // 16 targets per block
    const float* posb = pos + (size_t)b * N_NODES * 3;

    for (int n = threadIdx.x; n < N_NODES; n += 1024) {
        ppos[n] = make_float4(posb[3 * n], posb[3 * n + 1], posb[3 * n + 2], 0.f);
    }
    __syncthreads();

    const int wave = threadIdx.x >> 6;
    const int lane = threadIdx.x & 63;
    const int i = i0 + wave;
    const int ci = i >> 6;        // chunk containing self
    const int li = i & 63;        // lane of self within that chunk

    const float4 pi4 = ppos[i];
    const float pix = pi4.x, piy = pi4.y, piz = pi4.z;
    const unsigned self_or = (lane == li) ? 0xFFFFFFFFu : 0u;

    // ---- pass 1: per-lane top-4 (d2 bits only), branch-free ----
    unsigned m0 = 0xFFFFFFFFu, m1 = 0xFFFFFFFFu, m2 = 0xFFFFFFFFu, m3 = 0xFFFFFFFFu;
#pragma unroll 8
    for (int c = 0; c < 64; ++c) {
        const int j = (c << 6) | lane;
        const float4 p = ppos[j];
        // bitwise-exact fp32: ((dx*dx + dy*dy) + dz*dz), no FMA contraction
        const float dx = __fsub_rn(pix, p.x);
        const float dy = __fsub_rn(piy, p.y);
        const float dz = __fsub_rn(piz, p.z);
        const float d2 = __fadd_rn(__fadd_rn(__fmul_rn(dx, dx), __fmul_rn(dy, dy)),
                                   __fmul_rn(dz, dz));
        unsigned d2b = __float_as_uint(d2);
        if (c == ci) d2b |= self_or;          // self sorts after all real
        unsigned u = d2b, nm;
        nm = min(m0, u); u = max(m0, u); m0 = nm;
        nm = min(m1, u); u = max(m1, u); m1 = nm;
        nm = min(m2, u); u = max(m2, u); m2 = nm;
        m3 = min(m3, u);
    }

    // ---- radix-select: t = 40th smallest of the kept 4x64 values ----
    // invariant: acc = largest v with count(< v) < 40  ==>  final acc = s40.
    // All d2 bits < 2^31 (finite nonneg floats; every lane has >=63 real
    // candidates so no FFFF sentinels survive in m0..m3).
    unsigned acc = 0;
    for (int bit = 30; bit >= 0; --bit) {
        const unsigned test = acc | (1u << bit);
        const int cnt = __popcll(__ballot(m0 < test)) + __popcll(__ballot(m1 < test))
                      + __popcll(__ballot(m2 < test)) + __popcll(__ballot(m3 < test));
        if (cnt < K_NN) acc = test;
    }
    const unsigned t = acc;   // >= true 40th-smallest d2 bits (superset threshold)

    // ---- pass 2: sorted insert with fixed threshold ----
    unsigned Rhi = (lane == 0) ? 0u : 0xFFFFFFFFu;
    unsigned Rlo = (lane == 0) ? 0u : 0xFFFFFFFFu;

    for (int c = 0; c < 64; ++c) {
        const int j = (c << 6) | lane;
        const float4 p = ppos[j];
        const float dx = __fsub_rn(pix, p.x);
        const float dy = __fsub_rn(piy, p.y);
        const float dz = __fsub_rn(piz, p.z);
        const float d2 = __fadd_rn(__fadd_rn(__fmul_rn(dx, dx), __fmul_rn(dy, dy)),
                                   __fmul_rn(dz, dz));
        unsigned d2b = __float_as_uint(d2);
        if (c == ci) d2b |= self_or;

        unsigned long long mask = __ballot(d2b <= t);
        while (mask) INS_STEP(mask, d2b, Rhi, Rlo);
    }

    // Emit edges from lanes 1..40: src = global neighbor id, tgt = target id
    float* src_out = out + OUT_FEAT_ELEMS;
    float* tgt_out = src_out + EDGES;
    const int gi = b * N_NODES + i;
    const unsigned el = (unsigned)(lane - 1);
    if (el < K_NN) {
        src_out[(size_t)gi * K_NN + el] = (float)(b * N_NODES + (int)Rlo);
        tgt_out[(size_t)gi * K_NN + el] = (float)gi;
    }
}

// ---------------------------------------------------------------------------
// Kernel P: precompute W2 and W1 bf16 B-fragments into d_ws — R14, proven.
// ---------------------------------------------------------------------------
__global__ __launch_bounds__(256) void prep_kernel(const float* __restrict__ W2,
                                                   const float* __restrict__ W1,
                                                   unsigned short* __restrict__ ws)
{
    const int idx = blockIdx.x * 256 + threadIdx.x;   // 0..10239
    if (idx < 8192) {
        const int j    = idx & 7;
        const int lane = (idx >> 3) & 63;
        const int kt   = (idx >> 9) & 1;
        const int nt   = idx >> 10;
        const int k = kt * 32 + (lane >> 4) * 8 + j;
        const int n = nt * 16 + (lane & 15);
        ws[idx] = f2bf(W2[k * O_DIM + n]);
    } else if (idx < 8192 + 2048) {
        const int t = idx - 8192;
        const int j    = t & 7;
        const int lane = (t >> 3) & 63;
        const int nt   = t >> 9;          // 0..3
        const int k = (lane >> 4) * 8 + j;          // 0..31
        const int n = nt * 16 + (lane & 15);        // hidden channel
        ws[idx] = (k < 11) ? f2bf(W1[k * H_DIM + n]) : (unsigned short)0;
    }
}

// ---------------------------------------------------------------------------
// Kernel B: per-edge MLP, both layers MFMA — UNCHANGED from R14 (proven).
// ---------------------------------------------------------------------------
#define HSTR 72   // Hh row stride (bf16): 144 B
#define KSTR 40   // msg row stride (bf16): 80 B, 16B-aligned rows

__global__ __launch_bounds__(256, 4) void conv_kernel(
    const float* __restrict__ x, const float* __restrict__ pos,
    const unsigned short* __restrict__ w2f,   // d_ws: w2 frags [0,8192)
    const unsigned short* __restrict__ w1f,   // d_ws: w1 frags [8192,10240)
    const float* __restrict__ b1, const float* __restrict__ b2,
    float* __restrict__ out)
{
    __shared__ __align__(16) unsigned short Hh[4][48 * HSTR];    // 27648 B

    const int b    = blockIdx.x >> 10;
    const int i0   = (blockIdx.x & 1023) << 2;
    const int wave = threadIdx.x >> 6;
    const int lane = threadIdx.x & 63;
    const int quad = lane >> 4;
    const int col  = lane & 15;
    const int i    = i0 + wave;
    const int gi   = b * N_NODES + i;

    unsigned short* Hw = Hh[wave];

    // ---- phase 1: lane n (<48) gathers message row n, stages bf16 to LDS ----
    const float* src_edges = out + OUT_FEAT_ELEMS;
    if (lane < 48) {
        int j;
        if (lane < K_NN) j = (int)src_edges[(size_t)gi * K_NN + lane] - b * N_NODES;
        else             j = i;   // rows 40..47: self row + pad dups (max-safe)
        const float* xr = x + ((size_t)b * N_NODES + j) * F_IN;
        float4 xa = *(const float4*)xr;
        float4 xb = *(const float4*)(xr + 4);
        const float* pj = pos + ((size_t)b * N_NODES + j) * 3;
        const float* pi = pos + ((size_t)b * N_NODES + i) * 3;
        unsigned w[16];
#pragma unroll
        for (int t = 0; t < 16; ++t) w[t] = 0;
        w[0] = (unsigned)f2bf(xa.x) | ((unsigned)f2bf(xa.y) << 16);
        w[1] = (unsigned)f2bf(xa.z) | ((unsigned)f2bf(xa.w) << 16);
        w[2] = (unsigned)f2bf(xb.x) | ((unsigned)f2bf(xb.y) << 16);
        w[3] = (unsigned)f2bf(xb.z) | ((unsigned)f2bf(xb.w) << 16);
        w[4] = (unsigned)f2bf(pj[0] - pi[0]) | ((unsigned)f2bf(pj[1] - pi[1]) << 16);
        w[5] = (unsigned)f2bf(pj[2] - pi[2]);
        unsigned* mrow = (unsigned*)(Hw + lane * KSTR);
        *(uint4*)(mrow)      = make_uint4(w[0], w[1], w[2], w[3]);
        *(uint4*)(mrow + 4)  = make_uint4(w[4], w[5], w[6], w[7]);
        *(uint4*)(mrow + 8)  = make_uint4(w[8], w[9], w[10], w[11]);
        *(uint4*)(mrow + 12) = make_uint4(w[12], w[13], w[14], w[15]);
    }
    // same-wave ds_write -> ds_read: ordered by lgkmcnt, no barrier needed

    // ---- layer 1 via MFMA: H[48x64] = msg[48x32] . W1[32x64] ----
    bf16x8 Am[3];
#pragma unroll
    for (int mt = 0; mt < 3; ++mt)
        Am[mt] = *(const bf16x8*)&Hw[(mt * 16 + col) * KSTR + quad * 8];

    const bf16x8* W1f = (const bf16x8*)w1f;
    float hreg[12][4];
#pragma unroll
    for (int nt = 0; nt < 4; ++nt) {
        bf16x8 Bn = W1f[nt * 64 + lane];
        const float bias = b1[nt * 16 + col];
        f32x4 d0 = {bias, bias, bias, bias};
        f32x4 d1 = d0, d2 = d0;
        d0 = __builtin_amdgcn_mfma_f32_16x16x32_bf16(Am[0], Bn, d0, 0, 0, 0);
        d1 = __builtin_amdgcn_mfma_f32_16x16x32_bf16(Am[1], Bn, d1, 0, 0, 0);
        d2 = __builtin_amdgcn_mfma_f32_16x16x32_bf16(Am[2], Bn, d2, 0, 0, 0);
#pragma unroll
        for (int r = 0; r < 4; ++r) {
            hreg[nt * 3 + 0][r] = fmaxf(d0[r], 0.0f);
            hreg[nt * 3 + 1][r] = fmaxf(d1[r], 0.0f);
            hreg[nt * 3 + 2][r] = fmaxf(d2[r], 0.0f);
        }
    }

    // msg fully consumed -> overwrite region as Hh[row][hidden]
#pragma unroll
    for (int nt = 0; nt < 4; ++nt)
#pragma unroll
        for (int mt = 0; mt < 3; ++mt)
#pragma unroll
            for (int r = 0; r < 4; ++r)
                Hw[(mt * 16 + quad * 4 + r) * HSTR + nt * 16 + col] =
                    f2bf(hreg[nt * 3 + mt][r]);

    // ---- layer 2 via MFMA ----
    bf16x8 Af[3][2];
#pragma unroll
    for (int mt = 0; mt < 3; ++mt)
#pragma unroll
        for (int kt = 0; kt < 2; ++kt)
            Af[mt][kt] = *(const bf16x8*)&Hw[(mt * 16 + col) * HSTR + kt * 32 + quad * 8];

    const bf16x8* Bws = (const bf16x8*)w2f;
#pragma unroll
    for (int nt = 0; nt < 8; ++nt) {
        bf16x8 B0 = Bws[nt * 128 + lane];
        bf16x8 B1 = Bws[nt * 128 + 64 + lane];

        f32x4 c0 = {0.f, 0.f, 0.f, 0.f};
        f32x4 c1 = {0.f, 0.f, 0.f, 0.f};
        f32x4 c2 = {0.f, 0.f, 0.f, 0.f};
        c0 = __builtin_amdgcn_mfma_f32_16x16x32_bf16(Af[0][0], B0, c0, 0, 0, 0);
        c1 = __builtin_amdgcn_mfma_f32_16x16x32_bf16(Af[1][0], B0, c1, 0, 0, 0);
        c2 = __builtin_amdgcn_mfma_f32_16x16x32_bf16(Af[2][0], B0, c2, 0, 0, 0);
        c0 = __builtin_amdgcn_mfma_f32_16x16x32_bf16(Af[0][1], B1, c0, 0, 0, 0);
        c1 = __builtin_amdgcn_mfma_f32_16x16x32_bf16(Af[1][1], B1, c1, 0, 0, 0);
        c2 = __builtin_amdgcn_mfma_f32_16x16x32_bf16(Af[2][1], B1, c2, 0, 0, 0);

        float vm = c0[0];
        vm = fmaxf(vm, c0[1]); vm = fmaxf(vm, c0[2]); vm = fmaxf(vm, c0[3]);
        vm = fmaxf(vm, c1[0]); vm = fmaxf(vm, c1[1]); vm = fmaxf(vm, c1[2]); vm = fmaxf(vm, c1[3]);
        vm = fmaxf(vm, c2[0]); vm = fmaxf(vm, c2[1]); vm = fmaxf(vm, c2[2]); vm = fmaxf(vm, c2[3]);
        vm = fmaxf(vm, __shfl_xor(vm, 16));
        vm = fmaxf(vm, __shfl_xor(vm, 32));
        vm += b2[nt * 16 + col];

        if (lane < 16) out[(size_t)gi * O_DIM + nt * 16 + lane] = vm;
    }
}

// ---------------------------------------------------------------------------
extern "C" void kernel_launch(void* const* d_in, const int* in_sizes, int n_in,
                              void* d_out, int out_size, void* d_ws, size_t ws_size,
                              hipStream_t stream) {
    const float* x   = (const float*)d_in[0];
    const float* pos = (const float*)d_in[1];
    const float* W1  = (const float*)d_in[2];
    const float* b1  = (const float*)d_in[3];
    const float* W2  = (const float*)d_in[4];
    const float* b2  = (const float*)d_in[5];
    float* out = (float*)d_out;
    unsigned short* ws = (unsigned short*)d_ws;   // 10240 bf16 = 20.5 KB

    prep_kernel<<<40, 256, 0, stream>>>(W2, W1, ws);
    knn_kernel<<<(B_CLOUDS * N_NODES) / 16, 1024, 0, stream>>>(pos, out);
    conv_kernel<<<(B_CLOUDS * N_NODES) / 4, 256, 0, stream>>>(
        x, pos, ws, ws + 8192, b1, b2, out);
}